// Round 5
// baseline (2604.473 us; speedup 1.0000x reference)
//
#include <hip/hip_runtime.h>
#include <cstdint>
#include <cstddef>

// Problem constants
#define B_     2048
#define H_     256
#define S_     64
#define NSTEP  32
#define OUTS   33
#define N4H    1024           // 4*H gate cols, permuted n = j*4 + g
#define TSTEPS 96             // 64 encoder + 32 AR
#define XSTRIDE (S_ * H_)     // x0 batch-row stride at fixed t
#define NBLK   256            // total blocks (64 x 4): 1 block/CU on 256 CUs

typedef _Float16 f16;
typedef _Float16 f16x8 __attribute__((ext_vector_type(8)));
typedef float    f32x4 __attribute__((ext_vector_type(4)));
typedef unsigned long long u64;

__device__ __forceinline__ float sigm(float x)  { return 1.f / (1.f + __expf(-x)); }
__device__ __forceinline__ float tanh_(float x) { return 1.f - 2.f / (1.f + __expf(2.f * x)); }

// device-coherent (agent scope) 16B f16 load/store for the cross-block h exchange
__device__ __forceinline__ f16x8 ld_h16(const f16* p) {
    union { u64 q[2]; f16x8 v; } u;
    u.q[0] = __hip_atomic_load((const u64*)p,     __ATOMIC_RELAXED, __HIP_MEMORY_SCOPE_AGENT);
    u.q[1] = __hip_atomic_load((const u64*)p + 1, __ATOMIC_RELAXED, __HIP_MEMORY_SCOPE_AGENT);
    return u.v;
}
__device__ __forceinline__ void st_h16(f16* p, const f16* h8) {
    union { f16 h[8]; u64 q[2]; } u;
#pragma unroll
    for (int e = 0; e < 8; ++e) u.h[e] = h8[e];
    __hip_atomic_store((u64*)p,     u.q[0], __ATOMIC_RELAXED, __HIP_MEMORY_SCOPE_AGENT);
    __hip_atomic_store((u64*)p + 1, u.q[1], __ATOMIC_RELAXED, __HIP_MEMORY_SCOPE_AGENT);
}

// ---------------------------------------------------------------------------
// Prep: quantize + pack encoder weights [W_ih | W_hh] (K=512) into
// MFMA-B-fragment-major f16 layout; permuted gate cols n = j*4 + g.
//   WeP[((ct*16 + kk)*64 + q*16 + c15)*8 + e] = W[n = ct*16+c15][k = kk*32+q*8+e]
// ---------------------------------------------------------------------------
__global__ __launch_bounds__(256) void prep_kernel(
    const float* __restrict__ W_ih, const float* __restrict__ W_hh,
    const float* __restrict__ b_ih, const float* __restrict__ b_hh,
    f16* __restrict__ WeP, float* __restrict__ pb)
{
    int t = blockIdx.x * 256 + threadIdx.x;
    if (t < N4H * 64) {
        int n  = t >> 6;                // permuted col 0..1023
        int kc = (t & 63) * 8;          // k base 0..504
        int j = n >> 2, g = n & 3;
        const float* src = (kc < H_) ? &W_ih[(size_t)(g * H_ + j) * H_ + kc]
                                     : &W_hh[(size_t)(g * H_ + j) * H_ + kc - H_];
        f16x8 v;
#pragma unroll
        for (int e = 0; e < 8; ++e) v[e] = (f16)src[e];
        int ct = n >> 4, c15 = n & 15, kk = kc >> 5, q = (kc >> 3) & 3;
        *(f16x8*)&WeP[((size_t)(ct * 16 + kk) * 64 + q * 16 + c15) * 8] = v;
    } else if (t < N4H * 64 + N4H) {
        int n = t - N4H * 64;
        int j = n >> 2, g = n & 3;
        pb[n] = b_ih[g * H_ + j] + b_hh[g * H_ + j];
    }
}

// ---------------------------------------------------------------------------
// Persistent LSTM: all 96 steps in one plain-launched kernel.
//   grid (64, 4) = 256 blocks; __launch_bounds__(256,1) -> 1 block/CU -> all
//   co-resident at dispatch on 256 CUs. Hand-rolled grid barrier per step.
//   B frags: 256 VGPRs/lane, loaded ONCE. c: 8 fp32 regs/thread, never in mem.
//   AR phase uses h@(W_ih+W_hh)^T == [h|h]@[W_ih|W_hh]^T -> same weights.
// ---------------------------------------------------------------------------
__global__ __launch_bounds__(256, 1) void lstm_persistent(
    const float* __restrict__ x0,
    f16* __restrict__ hA, f16* __restrict__ hB,   // ping-pong h (hA zeroed)
    const f16* __restrict__ WeP, const float* __restrict__ pb,
    float* __restrict__ out, unsigned int* __restrict__ cnt)
{
    // sA (32 KB f16) and sEpi (33.3 KB f32) overlaid
    __shared__ __align__(16) unsigned char smem[32 * 260 * 4];
    f16*   sA   = (f16*)smem;
    float* sEpi = (float*)smem;

    const int tid = threadIdx.x;
    const int l   = tid & 63;
    const int w   = tid >> 6;
    const int b0  = blockIdx.x * 32;
    const int np  = blockIdx.y;

    // ---- B fragments: global -> VGPR, once ----
    f16x8 Bf[4][16];
#pragma unroll
    for (int f = 0; f < 4; ++f) {
        const int ct = np * 16 + w * 4 + f;
#pragma unroll
        for (int kk = 0; kk < 16; ++kk)
            Bf[f][kk] = *(const f16x8*)&WeP[((size_t)(ct * 16 + kk) * 64 + l) * 8];
    }

    // staging mapping: thread -> (row 0..31, 32-wide k segment)
    const int srow = tid >> 3;
    const int kseg = (tid & 7) * 32;
    const int smt = srow >> 4, slrow = srow & 15;
    const int kkX = kseg >> 5;              // 0..7

    // cell mapping: thread -> (row 0..31, 8 consecutive j)
    const int crow = tid >> 3;
    const int cjb  = (tid & 7) * 8;
    const int cbg  = b0 + crow;
    const int cjg  = np * 64 + cjb;

    float creg[8];
#pragma unroll
    for (int jj = 0; jj < 8; ++jj) creg[jj] = 0.f;

    const int q = l >> 4, c15 = l & 15;

    // ---- prologue: stage step-0 A = [x_0 | h(=0)] ----
    {
        const float* src = x0 + (size_t)(b0 + srow) * XSTRIDE + kseg;  // t = 0
#pragma unroll
        for (int qq = 0; qq < 4; ++qq) {
            float4 v0 = *(const float4*)(src + qq * 8);
            float4 v1 = *(const float4*)(src + qq * 8 + 4);
            f16x8 h8;
            h8[0]=(f16)v0.x; h8[1]=(f16)v0.y; h8[2]=(f16)v0.z; h8[3]=(f16)v0.w;
            h8[4]=(f16)v1.x; h8[5]=(f16)v1.y; h8[6]=(f16)v1.z; h8[7]=(f16)v1.w;
            *(f16x8*)&sA[((size_t)(smt * 16 + kkX) * 64 + qq * 16 + slrow) * 8] = h8;
        }
        const f16* hsrc = hA + (size_t)(b0 + srow) * H_ + kseg;
#pragma unroll
        for (int qq = 0; qq < 4; ++qq) {
            f16x8 h8 = ld_h16(hsrc + qq * 8);
            *(f16x8*)&sA[((size_t)(smt * 16 + 8 + kkX) * 64 + qq * 16 + slrow) * 8] = h8;
        }
    }

    for (int t = 0; t < TSTEPS; ++t) {
        __syncthreads();

        // ---- K loop: 128 MFMAs / wave, 2 ds_read_b128 per 8 MFMAs ----
        f32x4 acc[2][4];
#pragma unroll
        for (int fm = 0; fm < 2; ++fm)
#pragma unroll
            for (int f = 0; f < 4; ++f) acc[fm][f] = (f32x4){0.f, 0.f, 0.f, 0.f};
#pragma unroll
        for (int kk = 0; kk < 16; ++kk) {
            f16x8 a0 = *(const f16x8*)&sA[((size_t)(0 * 16 + kk) * 64 + l) * 8];
            f16x8 a1 = *(const f16x8*)&sA[((size_t)(1 * 16 + kk) * 64 + l) * 8];
#pragma unroll
            for (int f = 0; f < 4; ++f) {
                acc[0][f] = __builtin_amdgcn_mfma_f32_16x16x32_f16(a0, Bf[f][kk], acc[0][f], 0, 0, 0);
                acc[1][f] = __builtin_amdgcn_mfma_f32_16x16x32_f16(a1, Bf[f][kk], acc[1][f], 0, 0, 0);
            }
        }
        __syncthreads();   // sA dead -> sEpi

        // ---- epilogue: C layout (col = lane&15, row = quad*4 + r) -> LDS ----
#pragma unroll
        for (int fm = 0; fm < 2; ++fm)
#pragma unroll
            for (int f = 0; f < 4; ++f) {
                const int nl = w * 64 + f * 16 + c15;
#pragma unroll
                for (int r = 0; r < 4; ++r)
                    sEpi[(fm * 16 + q * 4 + r) * 260 + nl] = acc[fm][f][r];
            }
        __syncthreads();

        // ---- fused LSTM cell; c in registers ----
        f16* hOut = (t & 1) ? hA : hB;
        {
            float hbuf[8];
            f16   hf[8];
#pragma unroll
            for (int jj = 0; jj < 8; ++jj) {
                const int nl = (cjb + jj) * 4;
                f32x4 g4 = *(const f32x4*)&sEpi[crow * 260 + nl];
                const float* pbp = &pb[np * 256 + nl];
                float ig = sigm(g4[0] + pbp[0]);
                float fg = sigm(g4[1] + pbp[1]);
                float gg = tanh_(g4[2] + pbp[2]);
                float og = sigm(g4[3] + pbp[3]);
                float cn = fg * creg[jj] + ig * gg;
                float hn = og * tanh_(cn);
                creg[jj] = cn;
                hbuf[jj] = hn;
                hf[jj]   = (f16)hn;
            }
            st_h16(hOut + (size_t)cbg * H_ + cjg, hf);
            if (t >= S_ - 1) {   // output slot s = t - 63 (t=63 -> s=0)
                float* o = out + (size_t)cbg * (OUTS * H_) + (size_t)(t - (S_ - 1)) * H_ + cjg;
                *(f32x4*)o       = *(f32x4*)&hbuf[0];
                *(f32x4*)(o + 4) = *(f32x4*)&hbuf[4];
            }
        }
        __syncthreads();   // drains all waves' stores (vmcnt 0) before arrive

        if (t == TSTEPS - 1) break;

        // ---- grid barrier: arrive, overlap x_{t+1} staging, wait ----
        if (tid == 0)
            __hip_atomic_fetch_add(cnt, 1u, __ATOMIC_RELEASE, __HIP_MEMORY_SCOPE_AGENT);

        const int tn = t + 1;
        if (tn < S_) {   // encoder: pre-stage x_{tn} (no cross-block dependency)
            const float* src = x0 + (size_t)tn * H_ + (size_t)(b0 + srow) * XSTRIDE + kseg;
#pragma unroll
            for (int qq = 0; qq < 4; ++qq) {
                float4 v0 = *(const float4*)(src + qq * 8);
                float4 v1 = *(const float4*)(src + qq * 8 + 4);
                f16x8 h8;
                h8[0]=(f16)v0.x; h8[1]=(f16)v0.y; h8[2]=(f16)v0.z; h8[3]=(f16)v0.w;
                h8[4]=(f16)v1.x; h8[5]=(f16)v1.y; h8[6]=(f16)v1.z; h8[7]=(f16)v1.w;
                *(f16x8*)&sA[((size_t)(smt * 16 + kkX) * 64 + qq * 16 + slrow) * 8] = h8;
            }
        }

        if (tid == 0) {
            // bounded spin: fail visibly rather than hang if co-residency breaks
            long spins = 0;
            while (__hip_atomic_load(cnt, __ATOMIC_ACQUIRE, __HIP_MEMORY_SCOPE_AGENT)
                   < (unsigned)NBLK * (unsigned)tn) {
                __builtin_amdgcn_s_sleep(8);
                if (++spins > 160000000L) break;
            }
        }
        __syncthreads();

        // ---- stage h half (and x-half too when AR: A = [h|h]) ----
        {
            const f16* hsrc = hOut + (size_t)(b0 + srow) * H_ + kseg;
#pragma unroll
            for (int qq = 0; qq < 4; ++qq) {
                f16x8 h8 = ld_h16(hsrc + qq * 8);
                *(f16x8*)&sA[((size_t)(smt * 16 + 8 + kkX) * 64 + qq * 16 + slrow) * 8] = h8;
                if (tn >= S_)
                    *(f16x8*)&sA[((size_t)(smt * 16 + kkX) * 64 + qq * 16 + slrow) * 8] = h8;
            }
        }
    }
}

// ---------------------------------------------------------------------------
extern "C" void kernel_launch(void* const* d_in, const int* in_sizes, int n_in,
                              void* d_out, int out_size, void* d_ws, size_t ws_size,
                              hipStream_t stream) {
    const float* x0   = (const float*)d_in[0];
    const float* W_ih = (const float*)d_in[1];
    const float* W_hh = (const float*)d_in[2];
    const float* b_ih = (const float*)d_in[3];
    const float* b_hh = (const float*)d_in[4];
    float* out = (float*)d_out;

    // workspace (~3.1 MB)
    char* p = (char*)d_ws;
    unsigned int* cnt = (unsigned int*)p; p += 128;
    float* pb = (float*)p; p += (size_t)N4H * 4;
    f16* hA  = (f16*)p; p += (size_t)B_ * H_ * 2;
    f16* hB  = (f16*)p; p += (size_t)B_ * H_ * 2;
    f16* WeP = (f16*)p; p += (size_t)N4H * 512 * 2;

    hipMemsetAsync(cnt, 0, 128, stream);
    hipMemsetAsync(hA, 0, (size_t)B_ * H_ * 2, stream);

    const int prep_total = N4H * 64 + N4H;
    prep_kernel<<<dim3((prep_total + 255) / 256), dim3(256), 0, stream>>>(
        W_ih, W_hh, b_ih, b_hh, WeP, pb);

    lstm_persistent<<<dim3(B_ / 32, N4H / 256), dim3(256), 0, stream>>>(
        x0, hA, hB, WeP, pb, out, cnt);
}